// Round 1
// baseline (1682.701 us; speedup 1.0000x reference)
//
#include <hip/hip_runtime.h>

// Problem: out[j] = max(x[j], -c[rank_j]) per row, where rank_j = position of j
// in stable ascending sort of key = x*rho.  B=4096 rows, P=8192.
//
// Strategy: per-row MSD bucket (top 13 bits of monotone-u32 key, 8192 bins)
// + within-bin exact rank count on the residual 32 bits ((key<<13)|j, distinct).

constexpr int P_LEN  = 8192;   // row length == #bins (13 bits)
constexpr int BDIM   = 1024;   // threads per block
constexpr int EPT    = P_LEN / BDIM;  // 8 elements per thread

__device__ __forceinline__ unsigned fkey(float f) {
    unsigned u = __float_as_uint(f);
    // order-preserving map: negatives -> ~u (descending mag fixed), positives -> u|sign
    return (u & 0x80000000u) ? ~u : (u | 0x80000000u);
}

__global__ __launch_bounds__(BDIM)
void qp_rank_kernel(const float* __restrict__ x,
                    const float* __restrict__ rho,
                    const float* __restrict__ c,
                    float* __restrict__ out)
{
    __shared__ unsigned cnt[P_LEN];  // 32 KB: histogram -> exclusive bases -> bin ends
    __shared__ unsigned mem[P_LEN];  // 32 KB: scratch (scan) then bin-grouped members

    const int row  = blockIdx.x;
    const int t    = threadIdx.x;
    const int j0   = t * EPT;
    const int lane = t & 63;
    const int wid  = t >> 6;

    const float* __restrict__ xr   = x   + (size_t)row * P_LEN;
    const float* __restrict__ rr   = rho + (size_t)row * P_LEN;
    float*       __restrict__ outr = out + (size_t)row * P_LEN;

    // ---- phase 0: zero histogram (vectorized) ----
    uint4 z4 = make_uint4(0u, 0u, 0u, 0u);
    ((uint4*)cnt)[t * 2]     = z4;
    ((uint4*)cnt)[t * 2 + 1] = z4;
    __syncthreads();

    // ---- phase 1: load, compute keys, histogram ----
    float4 xa = ((const float4*)(xr + j0))[0];
    float4 xb = ((const float4*)(xr + j0))[1];
    float4 ra = ((const float4*)(rr + j0))[0];
    float4 rb = ((const float4*)(rr + j0))[1];
    float xs[EPT] = {xa.x, xa.y, xa.z, xa.w, xb.x, xb.y, xb.z, xb.w};
    float rs[EPT] = {ra.x, ra.y, ra.z, ra.w, rb.x, rb.y, rb.z, rb.w};
    unsigned key[EPT];
#pragma unroll
    for (int k = 0; k < EPT; ++k) {
        key[k] = fkey(xs[k] * rs[k]);
        atomicAdd(&cnt[key[k] >> 19], 1u);
    }
    __syncthreads();

    // ---- phase 2: exclusive scan of cnt (8192 bins) in place ----
    uint4 la = ((const uint4*)&cnt[j0])[0];
    uint4 lb = ((const uint4*)&cnt[j0])[1];
    unsigned l[EPT] = {la.x, la.y, la.z, la.w, lb.x, lb.y, lb.z, lb.w};
    unsigned s = 0;
#pragma unroll
    for (int k = 0; k < EPT; ++k) s += l[k];

    unsigned incl = s;
#pragma unroll
    for (int d = 1; d < 64; d <<= 1) {
        unsigned v = __shfl_up(incl, d, 64);
        if (lane >= d) incl += v;
    }
    if (lane == 63) mem[wid] = incl;            // wave totals (mem is free scratch here)
    __syncthreads();
    if (t == 0) {
        unsigned acc = 0;
        for (int w = 0; w < BDIM / 64; ++w) { unsigned v = mem[w]; mem[w] = acc; acc += v; }
    }
    __syncthreads();
    unsigned base = mem[wid] + (incl - s);      // exclusive prefix for this thread
    unsigned b0 = base, b1, b2, b3, b4, b5, b6, b7;
    b1 = b0 + l[0]; b2 = b1 + l[1]; b3 = b2 + l[2]; b4 = b3 + l[3];
    b5 = b4 + l[4]; b6 = b5 + l[5]; b7 = b6 + l[6];
    ((uint4*)&cnt[j0])[0] = make_uint4(b0, b1, b2, b3);
    ((uint4*)&cnt[j0])[1] = make_uint4(b4, b5, b6, b7);
    __syncthreads();   // also orders mem[wid] reads before scatter overwrites mem

    // ---- phase 3: scatter residuals into bin-grouped member list ----
#pragma unroll
    for (int k = 0; k < EPT; ++k) {
        unsigned b   = key[k] >> 19;
        unsigned pos = atomicAdd(&cnt[b], 1u);          // cnt[b] becomes end-of-bin
        mem[pos] = (key[k] << 13) | (unsigned)(j0 + k); // low19(key)<<13 | idx
    }
    __syncthreads();

    // ---- phase 4: rank by position order (wave-coherent bin sizes) ----
    uint4 ma = ((const uint4*)&mem[j0])[0];
    uint4 mb = ((const uint4*)&mem[j0])[1];
    unsigned myrem[EPT] = {ma.x, ma.y, ma.z, ma.w, mb.x, mb.y, mb.z, mb.w};

    // binary search: smallest b with cnt[b] > j0  (cnt[b] = end of bin b)
    int lob = 0, hib = P_LEN;
    while (lob < hib) {
        int mid = (lob + hib) >> 1;
        if (cnt[mid] > (unsigned)j0) hib = mid; else lob = mid + 1;
    }
    int b = lob;

#pragma unroll 1
    for (int k = 0; k < EPT; ++k) {
        const int p = j0 + k;
        while (cnt[b] <= (unsigned)p) ++b;              // advance to p's bin
        const unsigned lo = (b == 0) ? 0u : cnt[b - 1];
        const unsigned hi = cnt[b];
        const unsigned mr = myrem[k];
        unsigned r = lo;
        for (unsigned q = lo; q < hi; ++q)
            r += (mem[q] < mr) ? 1u : 0u;               // exact rank (values distinct)
        const unsigned j = mr & (P_LEN - 1);
        const float res = fmaxf(xr[j], -c[r]);
        outr[j] = res;
    }
}

extern "C" void kernel_launch(void* const* d_in, const int* in_sizes, int n_in,
                              void* d_out, int out_size, void* d_ws, size_t ws_size,
                              hipStream_t stream) {
    const float* x   = (const float*)d_in[0];
    const float* rho = (const float*)d_in[1];
    const float* c   = (const float*)d_in[2];
    float* out = (float*)d_out;
    const int rows = in_sizes[0] / P_LEN;   // 4096
    qp_rank_kernel<<<rows, BDIM, 0, stream>>>(x, rho, c, out);
}